// Round 6
// baseline (145.866 us; speedup 1.0000x reference)
//
#include <hip/hip_runtime.h>

// binary_decoder: bit-exact fp32 emulation of the reference's sequential
// carry-save adder (absmax == 0.0 verified rounds 1-5).
//
// Round-6 change (diagnosis: rounds 4 & 5 both sat at ~60 cyc/step; removing
// vcc changed nothing -> the binder is the DPP cross-lane dependent latency
// (~40 cyc) sitting on the one-step carry cycle h->dpp->t->h):
//  - Remap: 2 bit-lanes (j even/odd) per SIMT lane, 4 lanes per chain,
//    256 waves (1/CU). The even->odd carry is a register rename (free);
//    only odd->even crosses lanes. The dpp-containing recurrence cycle now
//    spans TWO steps (h_e -> t_o -> h_o -> dpp -> t_e -> h_e), amortizing
//    L_dpp/2 per step, and the dpp issues ~1.5 steps before its consumer.
//    New bound: issue ~15 VALU/step ~= 30 cyc vs 60 before.
//  - pk relayout to [g][col] bit-planes; main loads one coalesced uint2
//    (both j's bits) per lane per 32 steps.
//
// Exactness: a = bits&x == x*hard (x>=0, product exact); u = fp32(s+a);
// t_e = fma(craw, qmask, u) with craw*qmask in {0,1} exact -> single round
// == u+c; t_o = u + h_e_prev (h in {0,1} exact); t in [0,4) so
// h = floor(t*0.5) in {0,1}; s' = fma(-2,h,t) == t-2h exact on [2,4).

#define F_DIM 2048
#define K_DIM 4096
#define B_DIM 8
#define G     32            // steps per group = bits per packed dword
#define NG    (F_DIM / G)   // 64 groups
#define NBX   2             // rotating buffer depth (distance 1 group ~ 1000 cyc)

#define PK_BYTES (NG * K_DIM * 4)  // 1 MB: [g][col] dwords

__device__ __forceinline__ float dpp_row_shr1(float v) {
    // row_shr:1 (0x111), all rows/banks, bound_ctrl: out-of-row source -> 0
    int r = __builtin_amdgcn_update_dpp(0, __float_as_int(v), 0x111, 0xf, 0xf, true);
    return __int_as_float(r);
}

__device__ __forceinline__ int sext_bit(unsigned bits, int u) {
#if __has_builtin(__builtin_amdgcn_sbfe)
    return __builtin_amdgcn_sbfe((int)bits, (unsigned)u, 1u);  // v_bfe_i32
#else
    return ((int)(bits << (31 - u))) >> 31;
#endif
}

// ---------------- pass 1: pack (w >= 0.5) bits into [g][col] planes --------
// pk[f32*4096 + col] bit j = (w[f32*32+j][col] >= 0.5)
__global__ __launch_bounds__(64) void pack_kernel(const float* __restrict__ w,
                                                  unsigned* __restrict__ pk) {
    const int t   = threadIdx.x;       // 0..63 -> 4 consecutive columns
    const int ogq = blockIdx.x;        // 0..15 (256-column slab)
    const int f32 = blockIdx.y;        // 0..63

    const float4* w4 = (const float4*)(w + ogq * 256) + t; // +K_DIM/4 per row

    unsigned b0 = 0, b1 = 0, b2 = 0, b3 = 0;
#pragma unroll
    for (int j = 0; j < 32; ++j) {
        float4 v = w4[(f32 * 32 + j) * (K_DIM / 4)];       // coalesced 1KB/row
        b0 |= (v.x >= 0.5f ? 1u : 0u) << j;
        b1 |= (v.y >= 0.5f ? 1u : 0u) << j;
        b2 |= (v.z >= 0.5f ? 1u : 0u) << j;
        b3 |= (v.w >= 0.5f ? 1u : 0u) << j;
    }
    uint4* dst = (uint4*)(pk + f32 * K_DIM + ogq * 256 + t * 4);
    *dst = make_uint4(b0, b1, b2, b3);                     // coalesced 1KB
}

// ---------------- pass 2: the sequential chain -----------------------------
// lane = o_local*4 + q; lane handles columns col = og16*128 + o_local*8 + q*2
// (j = 2q, "even") and col+1 (j = 2q+1, "odd").
__global__ __launch_bounds__(64, 1) void csa_main(const float* __restrict__ x,
                                                  const unsigned* __restrict__ pk,
                                                  float* __restrict__ out) {
    const int lane = threadIdx.x;                 // 0..63
    const int og16 = blockIdx.x;                  // 0..31 (16 outputs each)
    const int b    = blockIdx.y;                  // 0..7
    const int q    = lane & 3;                    // lane within chain
    const int col  = og16 * 128 + (lane >> 2) * 8 + q * 2;

    // carry-in mask for the even j of q==0 (j0: carry-in is always 0; also
    // kills the foreign h_7 arriving from the previous chain's q==3 lane).
    const float qmask = (q == 0) ? 0.0f : 1.0f;

    // Opaque zero: keep the x address out of the SMEM (lgkmcnt) domain.
    int zero;
    asm volatile("v_mov_b32 %0, 0" : "=v"(zero));

    const unsigned* pkc = pk + col;                         // +K_DIM per group
    const float4*   xp4 = (const float4*)(x + b * F_DIM) + zero;

    uint2  bb[NBX];
    float4 xb[NBX][G / 4];

    // prologue: groups 0..NBX-1
#pragma unroll
    for (int p = 0; p < NBX; ++p) {
        bb[p] = *(const uint2*)(pkc + p * K_DIM);
#pragma unroll
        for (int qq = 0; qq < G / 4; ++qq)
            xb[p][qq] = xp4[p * (G / 4) + qq];
    }

    float s_e = 0.0f, s_o = 0.0f;   // running sums, even/odd j
    float he  = 0.0f;               // h_e(prev step) -> odd carry (rename)
    float craw = 0.0f;              // dpp(h_o(prev step)) -> even carry

    for (int g0 = 0; g0 < NG; g0 += NBX) {   // 32 iterations
#pragma unroll
        for (int p = 0; p < NBX; ++p) {
            const float*   xf = (const float*)&xb[p][0];
            const unsigned be = bb[p].x;
            const unsigned bo = bb[p].y;
#pragma unroll
            for (int u = 0; u < G; ++u) {
                const int xbits = __float_as_int(xf[u]);
                // odd path first: produce h_o and issue its dpp EARLY
                float a_o  = __int_as_float(sext_bit(bo, u) & xbits);
                float u_o  = s_o + a_o;          // fp32(s + a)
                float t_o  = u_o + he;           // fp32(u + c), c = h_e(f-1)
                float hm_o = t_o * 0.5f;
                float h_o  = __builtin_floorf(hm_o);
                float craw_n = dpp_row_shr1(h_o);        // consumed next step
                // even path: consume PREVIOUS step's dpp result LATE
                float a_e  = __int_as_float(sext_bit(be, u) & xbits);
                float u_e  = s_e + a_e;
                float t_e  = __builtin_fmaf(craw, qmask, u_e);  // == u + c
                float hm_e = t_e * 0.5f;
                float h_e  = __builtin_floorf(hm_e);
                s_o = __builtin_fmaf(-2.0f, h_o, t_o);   // == t - 2h, exact
                s_e = __builtin_fmaf(-2.0f, h_e, t_e);
                he   = h_e;
                craw = craw_n;
            }
            // refill for use NBX-1 groups later (clamped tail re-read)
            int gb = g0 + p + NBX;
            int gc = (gb < NG) ? gb : (NG - 1);
            bb[p] = *(const uint2*)(pkc + gc * K_DIM);
#pragma unroll
            for (int qq = 0; qq < G / 4; ++qq)
                xb[p][qq] = xp4[gc * (G / 4) + qq];
        }
    }

    // outputs: s then carry, both flat [b][col]; lane owns col, col+1.
    float2* so = (float2*)(out + b * K_DIM + col);
    *so = make_float2(s_e, s_o);
    float2* co = (float2*)(out + B_DIM * K_DIM + b * K_DIM + col);
    *co = make_float2(craw * qmask, he);   // c_e = h_o(2047) shifted+masked
}

// ---------------- fallback (round-5 kernel) if ws is too small -------------
#define U_FB  16
#define NB_FB 4
__global__ __launch_bounds__(64, 1) void csa_fallback(const float* __restrict__ x,
                                                      const float* __restrict__ weight,
                                                      float* __restrict__ out) {
    const int lane = threadIdx.x;
    const int og   = blockIdx.x + 8 * blockIdx.y;
    const int b    = blockIdx.z;
    const int k    = og * 64 + lane;
    const float lsbmask = ((lane & 7) == 0) ? 0.0f : 1.0f;
    int zero;
    asm volatile("v_mov_b32 %0, 0" : "=v"(zero));
    const float*  wp  = weight + k;
    const float4* xp4 = (const float4*)(x + b * F_DIM) + zero;
    float  wb[NB_FB][U_FB];
    float4 xb[NB_FB][U_FB / 4];
#pragma unroll
    for (int p = 0; p < NB_FB; ++p) {
#pragma unroll
        for (int u = 0; u < U_FB; ++u) wb[p][u] = wp[(p * U_FB + u) * K_DIM];
#pragma unroll
        for (int q = 0; q < U_FB / 4; ++q) xb[p][q] = xp4[(p * U_FB) / 4 + q];
    }
    float s = 0.0f, craw = 0.0f;
    for (int f0 = 0; f0 < F_DIM; f0 += NB_FB * U_FB) {
#pragma unroll
        for (int p = 0; p < NB_FB; ++p) {
            const float* xf = (const float*)&xb[p][0];
#pragma unroll
            for (int u = 0; u < U_FB; ++u) {
                float a  = (wb[p][u] >= 0.5f) ? xf[u] : 0.0f;
                float uu = s + a;
                float t  = fmaf(craw, lsbmask, uu);
                float h  = floorf(t * 0.5f);
                s = fmaf(-2.0f, h, t);
                craw = dpp_row_shr1(h);
            }
            int fb = f0 + p * U_FB + NB_FB * U_FB;
            int fc = (fb <= F_DIM - U_FB) ? fb : (F_DIM - U_FB);
#pragma unroll
            for (int u = 0; u < U_FB; ++u) wb[p][u] = wp[(fc + u) * K_DIM];
#pragma unroll
            for (int q = 0; q < U_FB / 4; ++q) xb[p][q] = xp4[fc / 4 + q];
        }
    }
    out[b * K_DIM + k]                 = s;
    out[B_DIM * K_DIM + b * K_DIM + k] = craw * lsbmask;
}

extern "C" void kernel_launch(void* const* d_in, const int* in_sizes, int n_in,
                              void* d_out, int out_size, void* d_ws, size_t ws_size,
                              hipStream_t stream) {
    (void)in_sizes; (void)n_in; (void)out_size;
    const float* x      = (const float*)d_in[0];
    const float* weight = (const float*)d_in[1];
    float* out          = (float*)d_out;

    if (ws_size >= (size_t)PK_BYTES && d_ws != nullptr) {
        unsigned* pk = (unsigned*)d_ws;
        pack_kernel<<<dim3(16, 64, 1), dim3(64), 0, stream>>>(weight, pk);
        // grid (og16=32, b=8): linear%8 is og16-determined -> the 8 b-copies
        // sharing a pk slab land on one XCD (L2 reuse).
        csa_main<<<dim3(32, 8, 1), dim3(64), 0, stream>>>(x, pk, out);
    } else {
        csa_fallback<<<dim3(8, 8, 8), dim3(64), 0, stream>>>(x, weight, out);
    }
}